// Round 14
// baseline (159.731 us; speedup 1.0000x reference)
//
#include <hip/hip_runtime.h>
#include <math.h>

#define B_    16
#define T_    512
#define D_    2048
#define DS_   4096
#define TG_   128            // t-groups of 4 rows
#define RS_   2052           // padded LDS row stride (floats)
#define EPS_  1e-8f
#define CLOG  16.0f          // drop weights < e^-16 (~1e-7 rel)

// ws (floats unless noted): inv_den[DS_] | g_u[DS_] | nr_u[DS_] | nout_s[DS_] i32 | smax_g[128] i32

__device__ __forceinline__ float softplus_f(float x) {
    return (x > 20.f) ? x : log1pf(expf(x));
}

__device__ __forceinline__ void glds16(const float* g, float* l) {
    __builtin_amdgcn_global_load_lds((const __attribute__((address_space(1))) void*)g,
                                     (__attribute__((address_space(3))) void*)l,
                                     16, 0, 0);
}

// Single-block prep: histogram + scan + slot tables + per-n params (coalesced)
// + ONE scattered array (nout_s).
__global__ __launch_bounds__(1024) void prep_kernel(const float* __restrict__ decay_rates,
                                                    float* __restrict__ inv_den,
                                                    float* __restrict__ g_u,
                                                    float* __restrict__ nr_u,
                                                    int* __restrict__ nout_s,
                                                    int* __restrict__ smax_g) {
    __shared__ int hist[64];     // counts -> later scatter cursor
    __shared__ int start_s[64];  // descending-exclusive starts
    __shared__ int tgl[16];
    const int tid = threadIdx.x;
    if (tid < 64) hist[tid] = 0;
    __syncthreads();
    int qv[4];
    #pragma unroll
    for (int k = 0; k < 4; ++k) {
        int n = tid + k * 1024;
        float r = softplus_f(decay_rates[n]);
        float hf = CLOG / r;
        int h = (hf >= 511.f) ? 511 : (int)hf;       // inf-safe cap
        qv[k] = h >> 3;
        atomicAdd(&hist[qv[k]], 1);
        float S = expm1f(-r * (float)T_) / expm1f(-r);   // exact geometric sum
        inv_den[n] = 1.0f / sqrtf(S + EPS_);             // coalesced, n-order
        g_u[n]     = expf(r);
        nr_u[n]    = -r;
    }
    __syncthreads();
    if (tid == 0) {                                   // exclusive scan, descending bucket
        int run = 0;
        for (int q = 63; q >= 0; --q) { start_s[q] = run; run += hist[q]; }
    }
    __syncthreads();
    if (tid < 64) hist[tid] = start_s[tid];           // reset cursor for scatter
    if (tid >= 64 && tid < 80) {                      // 16 slot leaders from boundaries
        int s = tid - 64;
        int R = s * 256;                              // leader rank (max-h element of slot)
        int qs = 0;
        for (int q = 63; q >= 0; --q) {
            int nxt = (q == 0) ? DS_ : start_s[q - 1];
            if (start_s[q] <= R && R < nxt) { qs = q; break; }
        }
        int h = (qs << 3) | 7;                        // conservative bound
        int tm = (511 - h) >> 2; if (tm < 0) tm = 0;
        tgl[s] = tm;
    }
    __syncthreads();                                  // cursor + tgl ready
    if (tid < TG_) {                                  // smax[tg] = #live slots (prefix)
        int c = 0;
        #pragma unroll
        for (int s = 0; s < 16; ++s) c += (tgl[s] <= tid) ? 1 : 0;
        smax_g[tid] = c;
    }
    #pragma unroll
    for (int k = 0; k < 4; ++k) {                     // the only scattered store
        int n = tid + k * 1024;
        int pos = atomicAdd(&hist[qv[k]], 1);
        nout_s[pos] = n;
    }
}

__global__ __launch_bounds__(256) void main_kernel(const float* __restrict__ z,
                                                   const float* __restrict__ g_u,
                                                   const float* __restrict__ nr_u,
                                                   const float* __restrict__ inv_den,
                                                   const int* __restrict__ idx_i,
                                                   const int* __restrict__ idx_j,
                                                   const int* __restrict__ nout_s,
                                                   const int* __restrict__ smax_g,
                                                   float* __restrict__ out) {
    __shared__ float rows[4 * RS_];                   // 32.8 KB -> 4 blocks/CU
    const int tg   = blockIdx.x;                      // 0..127
    const int b    = blockIdx.y;                      // 0..15
    const int tid  = threadIdx.x;
    const int wave = tid >> 6, lane = tid & 63;
    const int tb   = tg * 4;

    // Fire staging FIRST: wave w owns row w; 8 x 1KB fire-and-forget segments.
    const float* src = z + ((size_t)b * T_ + tb + wave) * D_ + lane * 4;
    float* dst = rows + wave * RS_;
    #pragma unroll
    for (int s = 0; s < 8; ++s)
        glds16(src + s * 256, dst + s * 256);

    const int smax = smax_g[tg];                      // block-uniform scalar
    const float kb0 = (float)(511 - tb);              // exponent at local row 0
    int pair[16], nidx[16]; float g[16], w0[16];
    #pragma unroll
    for (int s = 0; s < 16; ++s) {
        if (s < smax) {                               // uniform predicate, live prefix only
            int m = tid + s * 256;
            int n = nout_s[m];                        // coalesced; L2-hot
            nidx[s] = n;
            pair[s] = idx_i[n] | (idx_j[n] << 16);    // gathers hidden under staging wait
            g[s]    = g_u[n];
            w0[s]   = __expf(nr_u[n] * kb0) * inv_den[n];   // denominator folded in
        }
    }

    asm volatile("s_waitcnt vmcnt(0)" ::: "memory");
    __syncthreads();

    #pragma unroll
    for (int s = 0; s < 16; ++s) {
        if (s < smax) {
            int ci = pair[s] & 0xFFFF, cj = pair[s] >> 16;
            float vi0 = rows[ci],           vj0 = rows[cj];
            float vi1 = rows[RS_ + ci],     vj1 = rows[RS_ + cj];
            float vi2 = rows[2 * RS_ + ci], vj2 = rows[2 * RS_ + cj];
            float vi3 = rows[3 * RS_ + ci], vj3 = rows[3 * RS_ + cj];
            float gs = g[s];
            float h3 = vi3 * vj3;
            float h2 = fmaf(h3, gs, vi2 * vj2);
            float h1 = fmaf(h2, gs, vi1 * vj1);
            float h0 = fmaf(h1, gs, vi0 * vj0);
            atomicAdd(&out[b * DS_ + nidx[s]], w0[s] * h0);  // ~15 adds/address total
        }
    }
}

extern "C" void kernel_launch(void* const* d_in, const int* in_sizes, int n_in,
                              void* d_out, int out_size, void* d_ws, size_t ws_size,
                              hipStream_t stream) {
    const float* z  = (const float*)d_in[0];   // (16,512,2048) f32
    const float* dr = (const float*)d_in[1];   // (4096,) f32
    const int*   ii = (const int*)d_in[2];     // (4096,) i32
    const int*   jj = (const int*)d_in[3];     // (4096,) i32
    float* out = (float*)d_out;                // (16,4096) f32

    float* inv_den = (float*)d_ws;
    float* g_u     = inv_den + DS_;
    float* nr_u    = g_u + DS_;
    int*   nout_s  = (int*)(nr_u + DS_);
    int*   smax_g  = nout_s + DS_;

    hipMemsetAsync(d_out, 0, (size_t)out_size * sizeof(float), stream);  // graph-legal
    hipLaunchKernelGGL(prep_kernel, dim3(1), dim3(1024), 0, stream,
                       dr, inv_den, g_u, nr_u, nout_s, smax_g);
    hipLaunchKernelGGL(main_kernel, dim3(TG_, B_), dim3(256), 0, stream,
                       z, g_u, nr_u, inv_den, ii, jj, nout_s, smax_g, out);
}